// Round 1
// baseline (314.784 us; speedup 1.0000x reference)
//
#include <hip/hip_runtime.h>
#include <math.h>

#define SEQL 8192
#define NH 16
#define HD 1024           // NH * 64
#define TSEL 25

// ---- workspace layout (float offsets) ----
#define OFF_KVPART 0                         // 4*16*4096 = 262144 (zeroed)
#define OFF_KSUM   262144                    // 1024 (zeroed)
#define OFF_ZEND   263168
#define OFF_PK     263168                    // 16*256*64 = 262144
#define OFF_KWT    525312                    // 16*4096 shorts = 32768 floats
#define OFF_KSWZ   558080                    // 16*256*2048 shorts
#define OFF_PQ     0                         // overlays kvpart
#define OFF_LUT    131072                    // overlays kvpart

typedef __attribute__((ext_vector_type(8))) short bf16x8;
typedef __attribute__((ext_vector_type(4))) float f32x4;

static __device__ inline short f2bf(float f) {
    union { float f; unsigned u; } c; c.f = f;
    unsigned r = (c.u + 0x7FFFu + ((c.u >> 16) & 1u)) >> 16;
    return (short)r;
}
static __device__ inline bf16x8 cvt8(float4 a, float4 b) {
    bf16x8 r;
    r[0] = f2bf(a.x); r[1] = f2bf(a.y); r[2] = f2bf(a.z); r[3] = f2bf(a.w);
    r[4] = f2bf(b.x); r[5] = f2bf(b.y); r[6] = f2bf(b.z); r[7] = f2bf(b.w);
    return r;
}
static __device__ inline unsigned cvtpk(float a, float b) {
    unsigned r;
    asm("v_cvt_pk_bf16_f32 %0, %1, %2" : "=v"(r) : "v"(a), "v"(b));
    return r;
}
static __device__ inline float exp2a(float x) {
#if __has_builtin(__builtin_amdgcn_exp2f)
    return __builtin_amdgcn_exp2f(x);
#else
    float r; asm("v_exp_f32 %0, %1" : "=v"(r) : "v"(x)); return r;
#endif
}
static __device__ inline void load_lds16(const void* g, void* l) {
    __builtin_amdgcn_global_load_lds((const __attribute__((address_space(1))) unsigned int*)g,
                                     (__attribute__((address_space(3))) unsigned int*)l,
                                     16, 0, 0);
}

// K1: pre-pass — per (h,n): K tile -> bf16 swizzled; V tile -> V^T bf16 swizzled;
// fused pooled_k. UNCHANGED (keeps pk summation order bit-identical -> topk stable).
__global__ __launch_bounds__(256) void prep_kv(const float* __restrict__ k,
                                               const float* __restrict__ v,
                                               short* __restrict__ kswz,
                                               short* __restrict__ vswz,
                                               float* __restrict__ pk) {
    __shared__ float pcol[4][64];
    int b = blockIdx.x;            // h*256 + n
    int h = b >> 8, n = b & 255;
    int t = threadIdx.x;
    {   // K: thread = (r = t>>3, ch = t&7)
        int r = t >> 3, ch = t & 7;
        const float* src = k + (size_t)(n * 32 + r) * HD + h * 64 + ch * 8;
        float4 f0 = *(const float4*)src, f1 = *(const float4*)(src + 4);
        int f = r * 8 + (ch ^ (r & 7));
        *(bf16x8*)(kswz + (size_t)b * 2048 + f * 8) = cvt8(f0, f1);
        float s[8] = { f0.x, f0.y, f0.z, f0.w, f1.x, f1.y, f1.z, f1.w };
        #pragma unroll
        for (int j = 0; j < 8; j++) {
            s[j] += __shfl_xor(s[j], 8, 64);
            s[j] += __shfl_xor(s[j], 16, 64);
            s[j] += __shfl_xor(s[j], 32, 64);
        }
        if ((t & 63) < 8) {
            #pragma unroll
            for (int j = 0; j < 8; j++) pcol[t >> 6][(t & 7) * 8 + j] = s[j];
        }
    }
    {   // V^T
        int c = t >> 6, d = t & 63;
        const float* src = v + (size_t)(n * 32 + c * 8) * HD + h * 64 + d;
        bf16x8 val;
        #pragma unroll
        for (int j = 0; j < 8; j++) val[j] = f2bf(src[(size_t)j * HD]);
        int f = d * 4 + (c ^ ((d >> 1) & 3));
        *(bf16x8*)(vswz + (size_t)b * 2048 + f * 8) = val;
    }
    __syncthreads();
    if (t < 64)
        pk[(size_t)b * 64 + t] =
            (pcol[0][t] + pcol[1][t] + pcol[2][t] + pcol[3][t]) * (1.f / 32.f);
}

// K2: pooled_q (UNCHANGED — summation order preserved for topk stability)
__global__ void pool_q(const float* __restrict__ q, float* __restrict__ pq) {
    int b = blockIdx.x;
    int h = b >> 7, m = b & 127, d = threadIdx.x;
    const float* base = q + (size_t)m * 64 * HD + h * 64 + d;
    float s = 0.f;
    #pragma unroll 8
    for (int r = 0; r < 64; r++) s += base[(size_t)r * HD];
    pq[(size_t)b * 64 + d] = s * (1.f / 64.f);
}

// K3: scores + top-25. Score math identical (f64 accum, same order);
// rank-count loop vectorized float4; output position via ballot/popc instead
// of O(t) serial LDS prefix.
__global__ __launch_bounds__(256) void score_topk(const float* __restrict__ pq,
                                                  const float* __restrict__ pk,
                                                  int* __restrict__ lut) {
    __shared__ __align__(16) float pq_s[64];
    __shared__ __align__(16) float s_s[256];
    __shared__ int wcnt[4];
    int b = blockIdx.x;            // h*128 + m
    int h = b >> 7;
    int t = threadIdx.x;
    int lane = t & 63, w = t >> 6;
    if (t < 64) pq_s[t] = pq[(size_t)b * 64 + t];
    __syncthreads();
    const float* kr = pk + ((size_t)h * 256 + t) * 64;
    double acc = 0.0;
    #pragma unroll 8
    for (int d = 0; d < 64; d++) acc += (double)pq_s[d] * (double)kr[d];
    float sc = (float)acc;
    s_s[t] = sc;
    __syncthreads();
    int cnt = 0;
    float si = sc;
    #pragma unroll 4
    for (int j4 = 0; j4 < 64; j4++) {
        float4 sv = *(const float4*)&s_s[j4 * 4];
        int j = j4 * 4;
        cnt += (sv.x > si) || (sv.x == si && (j + 0) < t);
        cnt += (sv.y > si) || (sv.y == si && (j + 1) < t);
        cnt += (sv.z > si) || (sv.z == si && (j + 2) < t);
        cnt += (sv.w > si) || (sv.w == si && (j + 3) < t);
    }
    bool sel = cnt < TSEL;
    unsigned long long bal = __ballot(sel);
    if (lane == 0) wcnt[w] = __popcll(bal);
    __syncthreads();
    if (sel) {
        int off = __popcll(bal & ((1ull << lane) - 1ull));
        for (int i = 0; i < w; i++) off += wcnt[i];
        lut[(size_t)b * TSEL + off] = t;
    }
}

// K4: kvpart += k_fm^T v. Restructured: 4d x 4e register tile per thread
// (2 per-lane ds_read_b128 per row instead of 5 mixed DS ops), 32-row
// double-pass (halves LDS -> better occupancy), 2 chunks per block
// (halves atomic count). Softmax is exact-max, f32 sum-order change only.
__global__ __launch_bounds__(256) void lin_kv(const float* __restrict__ k,
                                              const float* __restrict__ v,
                                              float* __restrict__ kvpart,
                                              float* __restrict__ ksum) {
    __shared__ __align__(16) float kf[32][66];
    __shared__ __align__(16) float vv[32][66];
    int b = blockIdx.x;            // h*64 + c0 ; chunks c0 and c0+64
    int h = b >> 6, c0 = b & 63;
    int t = threadIdx.x;
    int lane = t & 63, w = t >> 6;
    int prow = t >> 3, c8 = (t & 7) * 8;
    int d0 = (lane & 15) * 4, e0 = (lane >> 4) * 4 + w * 16;
    float acc[16];
    #pragma unroll
    for (int i = 0; i < 16; i++) acc[i] = 0.f;
    float ks_acc = 0.f;
    for (int half = 0; half < 4; half++) {
        int lr = (c0 + (half >> 1) * 64) * 64 + (half & 1) * 32;
        const float* ksrc = k + (size_t)(lr + prow) * HD + h * 64 + c8;
        const float* vsrc = v + (size_t)(lr + prow) * HD + h * 64 + c8;
        float4 X0 = *(const float4*)ksrc;
        float4 X1 = *(const float4*)(ksrc + 4);
        float4 V0 = *(const float4*)vsrc;
        float4 V1 = *(const float4*)(vsrc + 4);
        *(float4*)&vv[prow][c8] = V0;
        *(float4*)&vv[prow][c8 + 4] = V1;
        float mx = fmaxf(fmaxf(fmaxf(X0.x, X0.y), fmaxf(X0.z, X0.w)),
                         fmaxf(fmaxf(X1.x, X1.y), fmaxf(X1.z, X1.w)));
        mx = fmaxf(mx, __shfl_xor(mx, 1, 64));
        mx = fmaxf(mx, __shfl_xor(mx, 2, 64));
        mx = fmaxf(mx, __shfl_xor(mx, 4, 64));
        X0.x = __expf(X0.x - mx); X0.y = __expf(X0.y - mx);
        X0.z = __expf(X0.z - mx); X0.w = __expf(X0.w - mx);
        X1.x = __expf(X1.x - mx); X1.y = __expf(X1.y - mx);
        X1.z = __expf(X1.z - mx); X1.w = __expf(X1.w - mx);
        float sm = (X0.x + X0.y + X0.z + X0.w) + (X1.x + X1.y + X1.z + X1.w);
        sm += __shfl_xor(sm, 1, 64);
        sm += __shfl_xor(sm, 2, 64);
        sm += __shfl_xor(sm, 4, 64);
        float inv = 1.f / sm;
        X0.x *= inv; X0.y *= inv; X0.z *= inv; X0.w *= inv;
        X1.x *= inv; X1.y *= inv; X1.z *= inv; X1.w *= inv;
        *(float4*)&kf[prow][c8] = X0;
        *(float4*)&kf[prow][c8 + 4] = X1;
        __syncthreads();
        #pragma unroll 8
        for (int l = 0; l < 32; l++) {
            float4 kd = *(const float4*)&kf[l][d0];
            float4 ve = *(const float4*)&vv[l][e0];
            acc[0]  += kd.x * ve.x; acc[1]  += kd.x * ve.y; acc[2]  += kd.x * ve.z; acc[3]  += kd.x * ve.w;
            acc[4]  += kd.y * ve.x; acc[5]  += kd.y * ve.y; acc[6]  += kd.y * ve.z; acc[7]  += kd.y * ve.w;
            acc[8]  += kd.z * ve.x; acc[9]  += kd.z * ve.y; acc[10] += kd.z * ve.z; acc[11] += kd.z * ve.w;
            acc[12] += kd.w * ve.x; acc[13] += kd.w * ve.y; acc[14] += kd.w * ve.z; acc[15] += kd.w * ve.w;
        }
        if (t < 64) {
            float s = 0.f;
            #pragma unroll 8
            for (int l = 0; l < 32; l++) s += kf[l][t];
            ks_acc += s;
        }
        __syncthreads();
    }
    float* dst = kvpart + ((size_t)(b & 3) * 16 + h) * 4096;
    #pragma unroll
    for (int i = 0; i < 4; i++)
        #pragma unroll
        for (int j = 0; j < 4; j++)
            atomicAdd(&dst[(d0 + i) * 64 + e0 + j], acc[i * 4 + j]);
    if (t < 64) atomicAdd(&ksum[h * 64 + t], ks_acc);
}

// K5: reduce partials + KWt = kvsum · W^T (bf16, transposed layout).
// Grid 16 -> 64 blocks (d split by 4); float4 dot; operand mapping chosen so
// kv reads are 2-way (free) and w reads are 4-addr multicast (conflict-free).
__global__ __launch_bounds__(256) void kw_mul(const float* __restrict__ kvpart,
                                              const float* __restrict__ W,
                                              short* __restrict__ kwt) {
    __shared__ __align__(16) float kv[16][68];
    __shared__ __align__(16) float wsm[64][68];
    int h = blockIdx.x >> 2, dq = blockIdx.x & 3;
    int t = threadIdx.x;
    for (int i = t; i < 1024; i += 256) {
        int dl = i >> 6, e = i & 63;
        float s = 0.f;
        #pragma unroll
        for (int p = 0; p < 4; p++)
            s += kvpart[((size_t)p * 16 + h) * 4096 + (dq * 16 + dl) * 64 + e];
        kv[dl][e] = s;
    }
    for (int i = t; i < 4096; i += 256) wsm[i >> 6][i & 63] = W[i];
    __syncthreads();
    int lane = t & 63, wi = t >> 6;
    int dl = lane & 15;
    int db = wi * 16 + (lane >> 4) * 4;
    #pragma unroll
    for (int j = 0; j < 4; j++) {
        int dd = db + j;
        float a = 0.f;
        #pragma unroll
        for (int e4 = 0; e4 < 16; e4++) {
            float4 kq = *(const float4*)&kv[dl][e4 * 4];
            float4 wq = *(const float4*)&wsm[dd][e4 * 4];
            a += kq.x * wq.x + kq.y * wq.y + kq.z * wq.z + kq.w * wq.w;
        }
        kwt[(size_t)h * 4096 + dd * 64 + dq * 16 + dl] = f2bf(a);
    }
}

// K6: fused block-sparse attention + linear branch.
// This round: VALU diet in the K-tile loop — v_cvt_pk_bf16_f32 P-pack
// (bit-identical RNE), 2x ds_write_b64 instead of 8 scalar short stores,
// exp2-folded constant (bit-identical to __expf(s*0.125)), s_setprio around
// MFMA clusters (T5).
__global__ __launch_bounds__(256) void sparse_attn_mfma(const float* __restrict__ q,
                                                        const short* __restrict__ kswz,
                                                        const short* __restrict__ vswz,
                                                        const int* __restrict__ lut,
                                                        const short* __restrict__ kwt,
                                                        const float* __restrict__ ksum,
                                                        const float* __restrict__ bproj,
                                                        float* __restrict__ out) {
    __shared__ __align__(16) short Kb[2][2048];
    __shared__ __align__(16) short Vb[2][2048];
    __shared__ __align__(16) short Pl[64][40];
    __shared__ int lut_s[TSEL];

    int b = blockIdx.x;
    int x = b & 7, jj = b >> 3;
    int h = x * 2 + (jj >> 7);       // XCD-affine
    int m = jj & 127;
    int t = threadIdx.x;
    int lane = t & 63, w = t >> 6;
    int l15 = lane & 15, quad = lane >> 4;

    if (t < TSEL) lut_s[t] = lut[(size_t)(h * 128 + m) * TSEL + t];
    __syncthreads();

    {
        size_t base = (size_t)(h * 256 + lut_s[0]) * 2048;
        load_lds16(kswz + base + t * 8, &Kb[0][t * 8]);
        load_lds16(vswz + base + t * 8, &Vb[0][t * 8]);
        load_lds16(kwt + (size_t)h * 4096 + t * 8, &Kb[1][t * 8]);
        load_lds16(kwt + (size_t)h * 4096 + 2048 + t * 8, &Vb[1][t * 8]);
    }

    const float* qrow = q + (size_t)(m * 64 + w * 16 + l15) * HD + h * 64;
    float4 x0 = *(const float4*)(qrow + quad * 8);
    float4 x1 = *(const float4*)(qrow + quad * 8 + 4);
    float4 x2 = *(const float4*)(qrow + 32 + quad * 8);
    float4 x3 = *(const float4*)(qrow + 32 + quad * 8 + 4);
    bf16x8 qa[2];
    qa[0] = cvt8(x0, x1);
    qa[1] = cvt8(x2, x3);

    float mx = fmaxf(fmaxf(fmaxf(x0.x, x0.y), fmaxf(x0.z, x0.w)),
                     fmaxf(fmaxf(x1.x, x1.y), fmaxf(x1.z, x1.w)));
    mx = fmaxf(mx, fmaxf(fmaxf(fmaxf(x2.x, x2.y), fmaxf(x2.z, x2.w)),
                         fmaxf(fmaxf(x3.x, x3.y), fmaxf(x3.z, x3.w))));
    mx = fmaxf(mx, __shfl_xor(mx, 16, 64));
    mx = fmaxf(mx, __shfl_xor(mx, 32, 64));
    x0.x = __expf(x0.x - mx); x0.y = __expf(x0.y - mx); x0.z = __expf(x0.z - mx); x0.w = __expf(x0.w - mx);
    x1.x = __expf(x1.x - mx); x1.y = __expf(x1.y - mx); x1.z = __expf(x1.z - mx); x1.w = __expf(x1.w - mx);
    x2.x = __expf(x2.x - mx); x2.y = __expf(x2.y - mx); x2.z = __expf(x2.z - mx); x2.w = __expf(x2.w - mx);
    x3.x = __expf(x3.x - mx); x3.y = __expf(x3.y - mx); x3.z = __expf(x3.z - mx); x3.w = __expf(x3.w - mx);
    float sm = (x0.x + x0.y + x0.z + x0.w) + (x1.x + x1.y + x1.z + x1.w)
             + (x2.x + x2.y + x2.z + x2.w) + (x3.x + x3.y + x3.z + x3.w);
    sm += __shfl_xor(sm, 16, 64);
    sm += __shfl_xor(sm, 32, 64);
    float qsc = 1.f / sm;
    float4 ka0 = *(const float4*)(ksum + h * 64 + quad * 8);
    float4 ka1 = *(const float4*)(ksum + h * 64 + quad * 8 + 4);
    float4 ka2 = *(const float4*)(ksum + h * 64 + 32 + quad * 8);
    float4 ka3 = *(const float4*)(ksum + h * 64 + 32 + quad * 8 + 4);
    float dq = x0.x * ka0.x + x0.y * ka0.y + x0.z * ka0.z + x0.w * ka0.w
             + x1.x * ka1.x + x1.y * ka1.y + x1.z * ka1.z + x1.w * ka1.w
             + x2.x * ka2.x + x2.y * ka2.y + x2.z * ka2.z + x2.w * ka2.w
             + x3.x * ka3.x + x3.y * ka3.y + x3.z * ka3.z + x3.w * ka3.w;
    dq += __shfl_xor(dq, 16, 64);
    dq += __shfl_xor(dq, 32, 64);
    float invd = 1.f / (dq * qsc + 1e-6f);
    x0.x *= qsc; x0.y *= qsc; x0.z *= qsc; x0.w *= qsc;
    x1.x *= qsc; x1.y *= qsc; x1.z *= qsc; x1.w *= qsc;
    x2.x *= qsc; x2.y *= qsc; x2.z *= qsc; x2.w *= qsc;
    x3.x *= qsc; x3.y *= qsc; x3.z *= qsc; x3.w *= qsc;
    bf16x8 qf[2];
    qf[0] = cvt8(x0, x1);
    qf[1] = cvt8(x2, x3);

    __syncthreads();                 // drains vmcnt: buf0 + KWt visible

    f32x4 Ol[4];
    #pragma unroll
    for (int dt = 0; dt < 4; dt++) Ol[dt] = (f32x4){0.f, 0.f, 0.f, 0.f};
    __builtin_amdgcn_s_setprio(1);
    #pragma unroll
    for (int dt = 0; dt < 4; dt++) {
        #pragma unroll
        for (int kc = 0; kc < 2; kc++) {
            int flat = (dt * 16 + l15) * 64 + kc * 32 + quad * 8;
            bf16x8 a = (dt < 2) ? *(const bf16x8*)&Kb[1][flat]
                                : *(const bf16x8*)&Vb[1][flat - 2048];
            Ol[dt] = __builtin_amdgcn_mfma_f32_16x16x32_bf16(a, qf[kc], Ol[dt], 0, 0, 0);
        }
    }
    __builtin_amdgcn_s_setprio(0);

    f32x4 O[4];
    #pragma unroll
    for (int dt = 0; dt < 4; dt++) O[dt] = (f32x4){0.f, 0.f, 0.f, 0.f};
    float l_i = 0.f;
    const f32x4 z = (f32x4){0.f, 0.f, 0.f, 0.f};
    const float EC = 1.44269504f * 0.125f;   // exact: 0.125*log2e, single rounding

    for (int ti = 0; ti < TSEL; ti++) {
        __syncthreads();              // B1: staging for ti complete
        int buf = ti & 1;
        if (ti + 1 < TSEL) {
            size_t base = (size_t)(h * 256 + lut_s[ti + 1]) * 2048;
            load_lds16(kswz + base + t * 8, &Kb[buf ^ 1][t * 8]);
            load_lds16(vswz + base + t * 8, &Vb[buf ^ 1][t * 8]);
        }
        int r0 = l15, r1 = 16 + l15;
        bf16x8 a00 = *(const bf16x8*)&Kb[buf][(r0 * 8 + (quad ^ (r0 & 7))) * 8];
        bf16x8 a01 = *(const bf16x8*)&Kb[buf][(r0 * 8 + ((4 + quad) ^ (r0 & 7))) * 8];
        bf16x8 a10 = *(const bf16x8*)&Kb[buf][(r1 * 8 + (quad ^ (r1 & 7))) * 8];
        bf16x8 a11 = *(const bf16x8*)&Kb[buf][(r1 * 8 + ((4 + quad) ^ (r1 & 7))) * 8];
        __builtin_amdgcn_s_setprio(1);
        f32x4 s0 = __builtin_amdgcn_mfma_f32_16x16x32_bf16(a00, qa[0], z, 0, 0, 0);
        s0 = __builtin_amdgcn_mfma_f32_16x16x32_bf16(a01, qa[1], s0, 0, 0, 0);
        f32x4 s1 = __builtin_amdgcn_mfma_f32_16x16x32_bf16(a10, qa[0], z, 0, 0, 0);
        s1 = __builtin_amdgcn_mfma_f32_16x16x32_bf16(a11, qa[1], s1, 0, 0, 0);
        __builtin_amdgcn_s_setprio(0);

        float p0[4], p1[4];
        float lsum = 0.f;
        #pragma unroll
        for (int r = 0; r < 4; r++) {
            p0[r] = exp2a(s0[r] * EC);
            p1[r] = exp2a(s1[r] * EC);
            lsum += p0[r] + p1[r];
        }
        lsum += __shfl_xor(lsum, 16, 64);
        lsum += __shfl_xor(lsum, 32, 64);
        l_i += lsum;

        uint2 pkA, pkB;
        pkA.x = cvtpk(p0[0], p0[1]); pkA.y = cvtpk(p0[2], p0[3]);
        pkB.x = cvtpk(p1[0], p1[1]); pkB.y = cvtpk(p1[2], p1[3]);
        *(uint2*)&Pl[w * 16 + l15][quad * 4] = pkA;
        *(uint2*)&Pl[w * 16 + l15][16 + quad * 4] = pkB;

        // B2: LDS-only barrier — async prefetch stays in flight
        asm volatile("s_waitcnt lgkmcnt(0)\n\ts_barrier" ::: "memory");

        bf16x8 pb = *(const bf16x8*)&Pl[w * 16 + l15][quad * 8];
        __builtin_amdgcn_s_setprio(1);
        #pragma unroll
        for (int dt = 0; dt < 4; dt++) {
            int d = dt * 16 + l15;
            bf16x8 va = *(const bf16x8*)&Vb[buf][(d * 4 + (quad ^ ((d >> 1) & 3))) * 8];
            O[dt] = __builtin_amdgcn_mfma_f32_16x16x32_bf16(va, pb, O[dt], 0, 0, 0);
        }
        __builtin_amdgcn_s_setprio(0);
    }

    float inv = 1.f / l_i;
    float* dst = out + (size_t)(m * 64 + w * 16 + l15) * HD + h * 64;
    #pragma unroll
    for (int dt = 0; dt < 4; dt++) {
        float4 bv = *(const float4*)(bproj + dt * 16 + quad * 4);
        float4 o;
        o.x = O[dt][0] * inv + Ol[dt][0] * invd + bv.x;
        o.y = O[dt][1] * inv + Ol[dt][1] * invd + bv.y;
        o.z = O[dt][2] * inv + Ol[dt][2] * invd + bv.z;
        o.w = O[dt][3] * inv + Ol[dt][3] * invd + bv.w;
        *(float4*)(dst + dt * 16 + quad * 4) = o;
    }
}

extern "C" void kernel_launch(void* const* d_in, const int* in_sizes, int n_in,
                              void* d_out, int out_size, void* d_ws, size_t ws_size,
                              hipStream_t stream) {
    const float* q  = (const float*)d_in[0];
    const float* k  = (const float*)d_in[1];
    const float* v  = (const float*)d_in[2];
    const float* W  = (const float*)d_in[3];
    const float* bp = (const float*)d_in[4];
    float* out = (float*)d_out;
    float* ws = (float*)d_ws;

    float* kvpart = ws + OFF_KVPART;
    float* ksum   = ws + OFF_KSUM;
    float* pk     = ws + OFF_PK;
    short* kwt    = (short*)(ws + OFF_KWT);
    short* kswz   = (short*)(ws + OFF_KSWZ);
    short* vswz   = kswz + (size_t)16 * 256 * 2048;
    float* pq     = ws + OFF_PQ;
    int*   lut    = (int*)(ws + OFF_LUT);

    hipMemsetAsync(ws, 0, OFF_ZEND * sizeof(float), stream);
    prep_kv<<<4096, 256, 0, stream>>>(k, v, kswz, vswz, pk);
    lin_kv<<<1024, 256, 0, stream>>>(k, v, kvpart, ksum);
    kw_mul<<<64, 256, 0, stream>>>(kvpart, W, kwt);
    pool_q<<<2048, 64, 0, stream>>>(q, pq);
    score_topk<<<2048, 256, 0, stream>>>(pq, pk, lut);
    sparse_attn_mfma<<<2048, 256, 0, stream>>>(q, kswz, vswz, lut, kwt, ksum, bp, out);
}